// Round 12
// baseline (231.270 us; speedup 1.0000x reference)
//
#include <hip/hip_runtime.h>

// out[m,n] = sum_k x[m,k] * (qw[k,n]*scale[n]) + bias[n]
// M=8192, K=1024, N=4096 fp32. Scale factors out of K-sum -> bf16 MFMA GEMM.
//   pass1 (merged): x fp32 -> bf16 [M][K]  and  qw [K][N] fp32 -> wT [N][K] bf16
//   pass2: 128x256 tile, BK=32, 8 waves of 64x64, 48 KiB LDS -> 2 blocks/CU
//          (acc=64 regs so ~115 total fits the 128-reg cap of 4 waves/SIMD --
//          the register-feasible fix of R10's spill disaster). R11's proven
//          K-loop: 1 barrier + 1 vmcnt(0) per tile, stage t+1 under MFMA,
//          setprio. Conflict-free 2-bit swizzle for 64B rows.

#define Mdim 8192
#define Ndim 4096
#define Kdim 1024
#define NT 32  // Kdim/32 K-tiles

typedef __attribute__((ext_vector_type(8))) short short8;
typedef __attribute__((ext_vector_type(4))) float floatx4;
typedef __attribute__((ext_vector_type(4))) unsigned short ushort4v;
typedef __attribute__((ext_vector_type(8))) unsigned short ushort8v;

__device__ inline unsigned short f2bf(float f) {
    unsigned int u = __builtin_bit_cast(unsigned int, f);
    u = (u + 0x7fffu + ((u >> 16) & 1u)) >> 16;
    return (unsigned short)u;
}

#define GLOAD_LDS16(gsrc, ldst)                                                             \
    __builtin_amdgcn_global_load_lds((const __attribute__((address_space(1))) void*)(gsrc), \
                                     (__attribute__((address_space(3))) void*)(ldst), 16, 0, 0)

// ---------------- pass 1: both conversions in one launch ----------------
__global__ __launch_bounds__(256) void cvt_kernel(const float* __restrict__ x,
                                                  const float* __restrict__ qw,
                                                  unsigned short* __restrict__ xb,
                                                  unsigned short* __restrict__ wT) {
    __shared__ unsigned short tile[64][66];
    if (blockIdx.x < 1024) {
        int bn = blockIdx.x & 63;
        int bk = blockIdx.x >> 6;
        int tx = threadIdx.x & 15;
        int ty = threadIdx.x >> 4;
        const float* src = qw + (size_t)(bk * 64) * Ndim + bn * 64 + tx * 4;
#pragma unroll
        for (int i = 0; i < 4; ++i) {
            int r = ty + i * 16;
            float4 v = *(const float4*)(src + (size_t)r * Ndim);
            tile[r][tx * 4 + 0] = f2bf(v.x);
            tile[r][tx * 4 + 1] = f2bf(v.y);
            tile[r][tx * 4 + 2] = f2bf(v.z);
            tile[r][tx * 4 + 3] = f2bf(v.w);
        }
        __syncthreads();
        unsigned short* dst = wT + (size_t)(bn * 64) * Kdim + bk * 64 + tx * 4;
#pragma unroll
        for (int i = 0; i < 4; ++i) {
            int r = ty + i * 16;
            ushort4v o;
            o[0] = tile[tx * 4 + 0][r];
            o[1] = tile[tx * 4 + 1][r];
            o[2] = tile[tx * 4 + 2][r];
            o[3] = tile[tx * 4 + 3][r];
            *(ushort4v*)(dst + (size_t)r * Kdim) = o;
        }
    } else {
        int i = (blockIdx.x - 1024) * 256 + threadIdx.x;  // exactly M*K/8 threads
        const float4* p = (const float4*)x + (size_t)i * 2;
        float4 a = p[0], b = p[1];
        ushort8v o;
        o[0] = f2bf(a.x); o[1] = f2bf(a.y); o[2] = f2bf(a.z); o[3] = f2bf(a.w);
        o[4] = f2bf(b.x); o[5] = f2bf(b.y); o[6] = f2bf(b.z); o[7] = f2bf(b.w);
        *((ushort8v*)xb + i) = o;
    }
}

// ---------------- pass 2: 128x256 GEMM, BK=32, 2 blocks/CU ----------------
// LDS/block 48 KiB: [dbuf 24576][A 8192 | B 16384]; row r at byte r*64 in its
// region (A: 128 M-rows; B: 256 N-rows). Staging: A = 1, B = 2 gload16/thread.
// Swizzle (64B rows): phys = L ^ (((L>>6)&3)<<4)  (row bits 0-1 -> slot bits
// 4-5). Quarter-wave (fixed lq, 16 consecutive rows) covers 8 bank-positions
// 2-way => conflict-free. Read side: ca = (lq ^ (la&3))<<4 (per-lane constant;
// wr*64/wc*64/m*16/ni*16 row terms are multiples of 4 -> don't touch row bits 0-1).
// Per K-tile: [vmcnt(0); s_barrier] [read 4 A + 4 B frags] [stage t+1 -> other
// buf] [setprio(1); 16 MFMA; setprio(0)].
__global__ __launch_bounds__(512, 4) void gemm_kernel(const unsigned short* __restrict__ xb,
                                                      const unsigned short* __restrict__ wT,
                                                      const float* __restrict__ scales,
                                                      const float* __restrict__ bias,
                                                      float* __restrict__ out) {
    extern __shared__ char ldsc[];

    // XCD-bijective swizzle: nwg = 1024, 1024 % 8 == 0
    int bid = blockIdx.x;
    int swz = (bid & 7) * 128 + (bid >> 3);
    int tile_n = swz & 15;   // fast: 16 consecutive blocks share the A panel (L2)
    int tile_m = swz >> 4;

    int tid = threadIdx.x;
    int wid = tid >> 6, lane = tid & 63;
    int wr = wid >> 2, wc = wid & 3;     // wave -> 64x64 sub-tile of 128x256
    int la = lane & 15, lq = lane >> 4;

    // ---- staging source offsets (dest linear, source inverse-swizzled) ----
    int dA = tid * 16;                                  // byte in A region (8 KB)
    int LA = dA ^ (((dA >> 6) & 3) << 4);
    int gA = (LA >> 6) * Kdim + ((LA & 63) >> 1);
    int gB[2];
#pragma unroll
    for (int i = 0; i < 2; ++i) {
        int db = tid * 16 + i * 8192;                   // byte in B region (16 KB)
        int LB = db ^ (((db >> 6) & 3) << 4);
        gB[i] = (LB >> 6) * Kdim + ((LB & 63) >> 1);
    }
    const unsigned short* aTile = xb + (size_t)tile_m * 128 * Kdim;
    const unsigned short* bTile = wT + (size_t)tile_n * 256 * Kdim;

    auto ISSUE = [&](int t) {   // 3 gload16/thread: A quarter + 2 B halves
        char* base = ldsc + (t & 1) * 24576;
        GLOAD_LDS16(aTile + t * 32 + gA, base + dA);
        GLOAD_LDS16(bTile + t * 32 + gB[0], base + 8192 + tid * 16);
        GLOAD_LDS16(bTile + t * 32 + gB[1], base + 8192 + tid * 16 + 8192);
    };

    // ---- ds_read addressing ----
    int ca = (lq ^ (la & 3)) << 4;           // swizzled slot byte (per-lane const)
    int arow = (wr * 64 + la) * 64;          // + m*1024
    int brow = wc * 4096 + la * 64;          // + ni*1024

    floatx4 acc[4][4] = {};
    short8 af[4], bf[4];

    // ---- prologue: stage tile0 (3 loads in flight) ----
    ISSUE(0);

#pragma unroll 1
    for (int t = 0; t < NT; ++t) {
        const char* abase = ldsc + (t & 1) * 24576;
        const char* bbase = abase + 8192;

        asm volatile("s_waitcnt vmcnt(0)" ::: "memory");   // tile t fully staged
        __builtin_amdgcn_s_barrier();                      // all waves' writes visible

#pragma unroll
        for (int m = 0; m < 4; ++m)
            af[m] = *(const short8*)(abase + arow + m * 1024 + ca);
#pragma unroll
        for (int n = 0; n < 4; ++n)
            bf[n] = *(const short8*)(bbase + brow + n * 1024 + ca);

        if (t + 1 < NT) ISSUE(t + 1);                      // stage t+1 -> other buf

        __builtin_amdgcn_s_setprio(1);
#pragma unroll
        for (int m = 0; m < 4; ++m)
#pragma unroll
            for (int n = 0; n < 4; ++n)
                acc[m][n] = __builtin_amdgcn_mfma_f32_16x16x32_bf16(af[m], bf[n],
                                                                    acc[m][n], 0, 0, 0);
        __builtin_amdgcn_s_setprio(0);
    }

    // ---- epilogue: out = acc * scale[n] + bias[n] ----
    size_t m_base = (size_t)tile_m * 128 + wr * 64;
    int n_base = tile_n * 256 + wc * 64;
#pragma unroll
    for (int ni = 0; ni < 4; ++ni) {
        int col = n_base + ni * 16 + la;
        float s = scales[col], bb2 = bias[col];
#pragma unroll
        for (int mi = 0; mi < 4; ++mi) {
            size_t row0 = m_base + mi * 16 + lq * 4;
#pragma unroll
            for (int v = 0; v < 4; ++v)
                out[(row0 + v) * Ndim + col] = acc[mi][ni][v] * s + bb2;
        }
    }
}

// ---------------- fallback ----------------
__global__ __launch_bounds__(256) void fallback_kernel(const float* __restrict__ x,
                                                       const float* __restrict__ qw,
                                                       const float* __restrict__ scales,
                                                       const float* __restrict__ bias,
                                                       float* __restrict__ out) {
    size_t idx = (size_t)blockIdx.x * 256 + threadIdx.x;
    size_t m = idx / Ndim, n = idx % Ndim;
    float sum = 0.f;
    for (int k = 0; k < Kdim; ++k) sum += x[m * Kdim + k] * qw[(size_t)k * Ndim + n];
    out[idx] = sum * scales[n] + bias[n];
}

extern "C" void kernel_launch(void* const* d_in, const int* in_sizes, int n_in,
                              void* d_out, int out_size, void* d_ws, size_t ws_size,
                              hipStream_t stream) {
    const float* x = (const float*)d_in[0];
    const float* qw = (const float*)d_in[1];
    const float* scales = (const float*)d_in[2];
    const float* bias = (const float*)d_in[3];
    float* out = (float*)d_out;

    size_t need = (size_t)Mdim * Kdim * 2 + (size_t)Ndim * Kdim * 2;  // 24 MB
    if (ws_size < need) {
        fallback_kernel<<<(Mdim * (size_t)Ndim) / 256, 256, 0, stream>>>(x, qw, scales, bias, out);
        return;
    }

    unsigned short* xb = (unsigned short*)d_ws;
    unsigned short* wT = xb + (size_t)Mdim * Kdim;

    (void)hipFuncSetAttribute((const void*)gemm_kernel,
                              hipFuncAttributeMaxDynamicSharedMemorySize, 49152);

    cvt_kernel<<<1024 + Mdim * Kdim / (8 * 256), 256, 0, stream>>>(x, qw, xb, wT);
    gemm_kernel<<<(Mdim / 128) * (Ndim / 256), 512, 49152, stream>>>(xb, wT, scales, bias, out);
}